// Round 8
// baseline (134.166 us; speedup 1.0000x reference)
//
#include <hip/hip_runtime.h>
#include <hip/hip_bf16.h>
#include <math.h>

#define SEQ_LEN  8192
#define HIDDEN   1024
#define NUM_SPANS 4096
#define MAX_W    32

__device__ __forceinline__ float dot4(float4 a, float4 b) {
    return a.x * b.x + a.y * b.y + a.z * b.z + a.w * b.w;
}

// ---------------------------------------------------------------------------
// K1: s_all[r] = dot(emb[r], attn_w) + bias for all 8192 rows, computed once
// (span scores depend only on the absolute row index). Wave-per-row,
// coalesced, butterfly-reduced. Pure 32 MB stream, ~5 us.
// ---------------------------------------------------------------------------
__global__ __launch_bounds__(256, 4) void row_score_kernel(
    const float* __restrict__ emb,      // (SEQ_LEN, HIDDEN)
    const float* __restrict__ attn_w,   // (HIDDEN,)
    const float* __restrict__ attn_b,   // (1,)
    float* __restrict__ s_all)          // (SEQ_LEN,) workspace
{
    const int wv2 = threadIdx.x >> 6;   // wave 0..3
    const int c   = threadIdx.x & 63;   // lane
    const int row = blockIdx.x * 4 + wv2;

    const float4* __restrict__ r4 = (const float4*)emb + (size_t)row * 256;
    const float4* __restrict__ wv = (const float4*)attn_w;

    float4 a0 = r4[c];
    float4 a1 = r4[c + 64];
    float4 a2 = r4[c + 128];
    float4 a3 = r4[c + 192];
    float4 w0 = wv[c];
    float4 w1 = wv[c + 64];
    float4 w2 = wv[c + 128];
    float4 w3 = wv[c + 192];

    float p = dot4(a0, w0) + dot4(a1, w1) + dot4(a2, w2) + dot4(a3, w3);
    #pragma unroll
    for (int off = 32; off > 0; off >>= 1)
        p += __shfl_xor(p, off, 64);
    if (c == 0) s_all[row] = p + attn_b[0];
}

// ---------------------------------------------------------------------------
// K2: per span, out = [emb[start] | emb[end] | sum_w wt[w]*emb[start+w]].
// Wave-per-half-span, zero barriers, zero LDS, SOFTWARE-PIPELINED row loop:
// iteration g issues group g+1's 8 float4 loads into n* and accumulates
// group g from c* (copied from the previous n*). Because the loaded values
// are consumed one iteration LATER, no compiler pass can serialize the batch
// into load->use pairs -- all 8 stay in flight across the whole body.
// R7 post-mortem: same-iteration loads + sched_barrier still collapsed to
// VGPR=36 (IR-level sinking); the loop-carried dependence makes the batch
// structural. Group-0 and end-row loads are issued BEFORE the softmax so
// their latency hides behind the s_all reads + shuffles + exp.
// ---------------------------------------------------------------------------
__global__ __launch_bounds__(256, 4) void span_out_kernel(
    const float* __restrict__ emb,      // (SEQ_LEN, HIDDEN)
    const int* __restrict__ starts,     // (NUM_SPANS,)
    const int* __restrict__ ends,       // (NUM_SPANS,)
    const float* __restrict__ s_all,    // (SEQ_LEN,) precomputed scores
    float* __restrict__ out)            // (NUM_SPANS, 3*HIDDEN)
{
    const int wv2 = threadIdx.x >> 6;       // wave 0..3
    const int c   = threadIdx.x & 63;       // lane
    const int s   = blockIdx.x * 2 + (wv2 >> 1);   // span
    const int h   = wv2 & 1;                       // half 0/1

    const int start = starts[s];
    const int end   = ends[s];
    const int wmax  = end - start;          // 0..31 inclusive width-1

    const float4* __restrict__ embr = (const float4*)emb;
    const int basecol = h * 128 + c;                    // float4 column
    const size_t sb = (size_t)start * 256 + basecol;    // row 0 address

    // ---- issue group-0 loads + end-row loads FIRST (fill the pipeline) ---
    float4 na0, na1, na2, na3, nb0, nb1, nb2, nb3;
    {
        const size_t q1 = (size_t)min(1, wmax) * 256;
        const size_t q2 = (size_t)min(2, wmax) * 256;
        const size_t q3 = (size_t)min(3, wmax) * 256;
        na0 = embr[sb];      nb0 = embr[sb + 64];
        na1 = embr[sb + q1]; nb1 = embr[sb + q1 + 64];
        na2 = embr[sb + q2]; nb2 = embr[sb + q2 + 64];
        na3 = embr[sb + q3]; nb3 = embr[sb + q3 + 64];
    }
    const size_t eb = sb + (size_t)wmax * 256;
    float4 ev0 = embr[eb];
    float4 ev1 = embr[eb + 64];

    // ---- softmax weights (overlaps group-0 load latency) -----------------
    const int w = c & 31;
    float sc = (w <= wmax) ? s_all[start + w] : -INFINITY;
    float m = sc;
    #pragma unroll
    for (int off = 16; off > 0; off >>= 1)
        m = fmaxf(m, __shfl_xor(m, off, 32));
    float e = __expf(sc - m);               // invalid -> exp(-inf) = 0
    float l = e;
    #pragma unroll
    for (int off = 16; off > 0; off >>= 1)
        l += __shfl_xor(l, off, 32);
    const float wt = e / l;                 // lane w (and w+32) holds wt[w]

    float4 acc0 = make_float4(0.f, 0.f, 0.f, 0.f);
    float4 acc1 = make_float4(0.f, 0.f, 0.f, 0.f);
    float4 sv0 = na0, sv1 = nb0;            // start row = group 0 slot 0

    const int ng = (wmax >> 2) + 1;         // groups of 4 rows: 1..8

    #pragma unroll 1
    for (int g = 0; g < ng; ++g) {
        // rotate: current <- previously-issued loads
        float4 a0 = na0, a1 = na1, a2 = na2, a3 = na3;
        float4 b0 = nb0, b1 = nb1, b2 = nb2, b3 = nb3;

        // issue next group's loads (consumed NEXT iteration: the batch is
        // loop-carried, the compiler cannot serialize it)
        if (g + 1 < ng) {
            const int r0 = 4 * (g + 1);
            const size_t q0 = (size_t)r0 * 256;
            const size_t q1 = (size_t)min(r0 + 1, wmax) * 256;
            const size_t q2 = (size_t)min(r0 + 2, wmax) * 256;
            const size_t q3 = (size_t)min(r0 + 3, wmax) * 256;
            na0 = embr[sb + q0]; nb0 = embr[sb + q0 + 64];
            na1 = embr[sb + q1]; nb1 = embr[sb + q1 + 64];
            na2 = embr[sb + q2]; nb2 = embr[sb + q2 + 64];
            na3 = embr[sb + q3]; nb3 = embr[sb + q3 + 64];
        }

        // accumulate group g (rows beyond wmax get weight exactly 0; their
        // loads were clamped onto row wmax, so values are defined)
        const int r0 = 4 * g;
        const float t0 = __shfl(wt, r0 & 31, 64);
        const float t1 = (r0 + 1 <= wmax) ? __shfl(wt, (r0 + 1) & 31, 64) : 0.f;
        const float t2 = (r0 + 2 <= wmax) ? __shfl(wt, (r0 + 2) & 31, 64) : 0.f;
        const float t3 = (r0 + 3 <= wmax) ? __shfl(wt, (r0 + 3) & 31, 64) : 0.f;
        acc0.x += t0*a0.x + t1*a1.x + t2*a2.x + t3*a3.x;
        acc0.y += t0*a0.y + t1*a1.y + t2*a2.y + t3*a3.y;
        acc0.z += t0*a0.z + t1*a1.z + t2*a2.z + t3*a3.z;
        acc0.w += t0*a0.w + t1*a1.w + t2*a2.w + t3*a3.w;
        acc1.x += t0*b0.x + t1*b1.x + t2*b2.x + t3*b3.x;
        acc1.y += t0*b0.y + t1*b1.y + t2*b2.y + t3*b3.y;
        acc1.z += t0*b0.z + t1*b1.z + t2*b2.z + t3*b3.z;
        acc1.w += t0*b0.w + t1*b1.w + t2*b2.w + t3*b3.w;
    }

    // ---- stores (all coalesced: 64 lanes x 16 B contiguous) --------------
    float4* __restrict__ o4 = (float4*)out + (size_t)s * 768;
    o4[basecol]            = sv0;
    o4[basecol + 64]       = sv1;
    o4[256 + basecol]      = ev0;
    o4[256 + basecol + 64] = ev1;
    o4[512 + basecol]      = acc0;
    o4[512 + basecol + 64] = acc1;
}

extern "C" void kernel_launch(void* const* d_in, const int* in_sizes, int n_in,
                              void* d_out, int out_size, void* d_ws, size_t ws_size,
                              hipStream_t stream) {
    const float* emb    = (const float*)d_in[0];
    const int*   starts = (const int*)d_in[1];
    const int*   ends   = (const int*)d_in[2];
    const float* attn_w = (const float*)d_in[3];
    const float* attn_b = (const float*)d_in[4];
    float* out   = (float*)d_out;
    float* s_all = (float*)d_ws;        // 8192 floats = 32 KB scratch

    row_score_kernel<<<SEQ_LEN / 4, 256, 0, stream>>>(emb, attn_w, attn_b, s_all);
    span_out_kernel<<<NUM_SPANS / 2, 256, 0, stream>>>(emb, starts, ends, s_all, out);
}